// Round 2
// baseline (404.323 us; speedup 1.0000x reference)
//
#include <hip/hip_runtime.h>
#include <hip/hip_bf16.h>

// Problem constants (ResNet-50 CBP head)
#define BATCH 8
#define CH    2048
#define LSP   784          // H*W = 28*28
#define KPAD  800          // pad K to 25*32 for MFMA k-steps
#define KSTEPS (KPAD/32)   // 25
#define DDIM  8192         // count-sketch dim (power of 2)
#define NCLS  200
#define NTILE 16           // 2048/128 tiles per dim
#define NPAIR 136          // NTILE*(NTILE+1)/2 symmetric tile pairs
#define NSLOT 68           // blocks per batch; each block = 2 pairs, exclusive slot

typedef _Float16 f16x8 __attribute__((ext_vector_type(8)));
typedef _Float16 f16x4 __attribute__((ext_vector_type(4)));
typedef float    f32x4 __attribute__((ext_vector_type(4)));

#define FATOMIC(p, v) unsafeAtomicAdd((p), (v))

// ---------------------------------------------------------------------------
// Kernel 1: convert x (fp32 [B,C,784]) to fp16 [B,C,KPAD] (zero-pad K).
// fp16 (11-bit mantissa) keeps Gram rel-err ~1e-4 -> single MFMA, no hi/lo.
// Zero-inits norm, seeds logits with bias. part needs NO init: every slot is
// fully overwritten by exactly one gram block (plain stores).
// ---------------------------------------------------------------------------
__global__ __launch_bounds__(256) void split_kernel(
    const float* __restrict__ x,
    _Float16* __restrict__ xh,
    float* __restrict__ norm,
    const float* __restrict__ bc, float* __restrict__ out)
{
    int idx = blockIdx.x * 256 + threadIdx.x;          // vec4 index
    if (idx < BATCH) norm[idx] = 0.0f;
    if (idx < BATCH * NCLS) out[idx] = bc[idx % NCLS]; // bias-seed logits
    if (idx >= BATCH * CH * KPAD / 4) return;
    int v  = idx * 4;
    int bc_ = v / KPAD;
    int l  = v - bc_ * KPAD;                           // multiple of 4
    float4 xv = make_float4(0.f, 0.f, 0.f, 0.f);
    if (l < LSP)                                       // LSP%4==0: uniform per vec
        xv = *(const float4*)&x[(size_t)bc_ * LSP + l];
    f16x4 hv;
    hv[0] = (_Float16)xv.x; hv[1] = (_Float16)xv.y;
    hv[2] = (_Float16)xv.z; hv[3] = (_Float16)xv.w;
    *(f16x4*)&xh[v] = hv;
}

// ---------------------------------------------------------------------------
// Kernel 2: symmetric Gram tiles (fp16 MFMA, fragments DIRECT from global)
// + count-sketch scatter.
// R2 theory: R0/R1's per-pair latency (~115us, all pipes <5%) was the
// barrier-synchronized global_load_lds->drain->ds_read->MFMA k-loop exposing
// ~11k cyc of latency per k-step. Fix: no LDS tiles at all. Each wave loads
// its A/B fragments straight to VGPRs (16 rows x 64B segments, L2-resident:
// 3.3 MB/batch/XCD). ~2x read amplification across waves, but the k-loop has
// ZERO barriers and the compiler software-pipelines loads under MFMA; waves
// and blocks de-phase so scatter (DS pipe) overlaps k-loops (VMEM+MFMA).
// LDS 34 KB (bins 32 + meta 2) -> 3 blocks/CU.
// grid = 544: batch = id&7 (one batch per XCD), pgrp = id>>3 owns pairs
// {pgrp, pgrp+68} and flushes once to its EXCLUSIVE part slot (plain stores).
// ---------------------------------------------------------------------------
__global__ __launch_bounds__(256, 3) void gram_scatter_kernel(
    const _Float16* __restrict__ xh,
    const int*   __restrict__ h1, const float* __restrict__ s1,
    const int*   __restrict__ h2, const float* __restrict__ s2,
    float* __restrict__ part)
{
    __shared__ float bins[DDIM];                             // 32 KB
    __shared__ float4 metaA[128];                            // 2 KB

    const int tid  = threadIdx.x;
    const int lane = tid & 63;
    const int wv   = tid >> 6;
    const int b    = blockIdx.x & 7;       // batch in low bits -> one batch/XCD
    const int pgrp = blockIdx.x >> 3;      // slot index, 0..67

    for (int i = tid; i < DDIM; i += 256) bins[i] = 0.0f;
    // (first __syncthreads below orders this before any scatter ds_add)

    const int wrow = (wv >> 1) * 64;    // wave's 64x64 subtile origin
    const int wcol = (wv & 1) * 64;
    const int rsel = lane & 15;
    const int klane = (lane >> 4) * 8;  // k element offset within a k-step

#pragma unroll 1
    for (int pp = 0; pp < 2; ++pp) {
        const int pidx = pgrp + pp * NSLOT;   // two pairs per block, same batch

        // Triangular decode: pidx in [0,136) -> (tM, tN), tM <= tN, row-major
        int tM = 0, tN = 0;
        {
            int i = pidx;
#pragma unroll 1
            for (int t = 0; t < NTILE; ++t) {
                int cnt = NTILE - t;
                if (i < cnt) { tM = t; tN = t + i; break; }
                i -= cnt;
            }
        }
        const bool diag = (tM == tN);

        // MFMA fragment addresses, straight from global:
        // A frag: row = tM*128 + wrow + i*16 + (lane&15), k = k0 + (lane>>4)*8
        // (identical element->lane mapping the old LDS path produced, so the
        //  MFMA semantics and scatter layout are unchanged bit-for-bit)
        const _Float16* baseA = xh + ((size_t)b * CH + (size_t)tM * 128) * KPAD + klane;
        const _Float16* baseB = xh + ((size_t)b * CH + (size_t)tN * 128) * KPAD + klane;
        const _Float16* pa[4];
        const _Float16* pb[4];
#pragma unroll
        for (int i = 0; i < 4; ++i) {
            pa[i] = baseA + (size_t)(wrow + i * 16 + rsel) * KPAD;
            pb[i] = baseB + (size_t)(wcol + i * 16 + rsel) * KPAD;
        }

        f32x4 acc[4][4];
        const f32x4 zv = {0.0f, 0.0f, 0.0f, 0.0f};
#pragma unroll
        for (int mi = 0; mi < 4; ++mi)
#pragma unroll
            for (int ni = 0; ni < 4; ++ni) acc[mi][ni] = zv;

        // Pure register k-loop: 8 x global_load_dwordx4 + 16 MFMA per step,
        // no barriers, no LDS. unroll 5 (25=5x5) gives the scheduler a window
        // to pipeline next-chunk loads under current-chunk MFMAs.
#pragma unroll 5
        for (int s = 0; s < KSTEPS; ++s) {
            f16x8 ah[4], bh[4];
#pragma unroll
            for (int i = 0; i < 4; ++i) {
                ah[i] = *(const f16x8*)(pa[i] + s * 32);
                bh[i] = *(const f16x8*)(pb[i] + s * 32);
            }
#pragma unroll
            for (int mi = 0; mi < 4; ++mi)
#pragma unroll
                for (int ni = 0; ni < 4; ++ni)
                    acc[mi][ni] = __builtin_amdgcn_mfma_f32_16x16x32_f16(ah[mi], bh[ni], acc[mi][ni], 0, 0, 0);
        }

        // Barrier 1: for pp=0 orders bins zero-init before the first ds_adds;
        // for pp=1 ensures all waves finished the PREVIOUS scatter (incl.
        // their metaA reads) before metaA is overwritten below.
        __syncthreads();

        // Stage scatter meta for this tile's 128 c1-rows into LDS.
        if (tid < 128) {
            int c1 = tM * 128 + tid;
            metaA[tid] = make_float4(s1[c1], __int_as_float(h1[c1]),
                                     s2[c1], __int_as_float(h2[c1]));
        }
        __syncthreads();   // metaA visible

        // Scatter the 128x128 Gram tile into the LDS histogram.
        // C/D layout (m89-verified): col = lane&15, row = (lane>>4)*4 + reg
        // Off-diagonal pair: each entry contributes twice (G symmetric).
        const int c2b = tN * 128 + wcol + rsel;
        const int rowsel = wrow + ((lane >> 4) << 2);
        int   h1c[4], h2c[4]; float s1c[4], s2c[4];
#pragma unroll
        for (int ni = 0; ni < 4; ++ni) {
            int c2 = c2b + ni * 16;
            h1c[ni] = h1[c2]; s1c[ni] = s1[c2];
            h2c[ni] = h2[c2]; s2c[ni] = s2[c2];
        }
#pragma unroll
        for (int mi = 0; mi < 4; ++mi) {
#pragma unroll
            for (int r = 0; r < 4; ++r) {
                float4 m = metaA[rowsel + mi * 16 + r];    // one ds_read_b128
                const float s1r = m.x, s2r = m.z;
                const int h1r = __float_as_int(m.y);
                const int h2r = __float_as_int(m.w);
#pragma unroll
                for (int ni = 0; ni < 4; ++ni) {
                    float g = acc[mi][ni][r];
                    FATOMIC(&bins[(h1r + h2c[ni]) & (DDIM - 1)], s1r * s2c[ni] * g);
                    if (!diag)
                        FATOMIC(&bins[(h1c[ni] + h2r) & (DDIM - 1)], s1c[ni] * s2r * g);
                }
            }
        }
        // No barrier here: this wave proceeds to pair 1's k-loop (VMEM/MFMA
        // pipes) while other waves finish scattering (DS pipe) -- the next
        // barrier is pair 1's pre-metaA __syncthreads.
    }

    __syncthreads();   // all scatters into bins complete

    // Flush to this block's EXCLUSIVE part slot: plain coalesced float4
    // stores (no atomics, no zero-check, no init needed).
    float* pbase = part + ((size_t)(pgrp * BATCH + b) * DDIM);
    for (int i = tid; i < DDIM / 4; i += 256)
        *(float4*)&pbase[i * 4] = *(const float4*)&bins[i * 4];
}

// ---------------------------------------------------------------------------
// Kernel 3: y[b,d] = sum over 68 part slots; accumulate norm[b] += sum|y|.
// grid 64 x 256: one float4 of d per thread. batch = blockIdx&7 so each
// batch's reduce blocks land on the XCD whose L2 holds that batch's part
// lines (written by the gram blocks with the same &7 mapping).
// ---------------------------------------------------------------------------
__global__ __launch_bounds__(256) void reduce_kernel(
    const float* __restrict__ part, float* __restrict__ y,
    float* __restrict__ norm)
{
    const int tid = threadIdx.x;
    const int b  = blockIdx.x & 7;
    const int d0 = (((blockIdx.x >> 3) * 256) + tid) * 4;  // float4 slice
    float4 s = make_float4(0.f, 0.f, 0.f, 0.f);
#pragma unroll 4
    for (int p = 0; p < NSLOT; ++p) {
        float4 v = *(const float4*)&part[((size_t)p * BATCH + b) * DDIM + d0];
        s.x += v.x; s.y += v.y; s.z += v.z; s.w += v.w;
    }
    *(float4*)&y[(size_t)b * DDIM + d0] = s;
    float ab = fabsf(s.x) + fabsf(s.y) + fabsf(s.z) + fabsf(s.w);
    __shared__ float red[256];
    red[tid] = ab;
    __syncthreads();
    for (int st = 128; st > 0; st >>= 1) {
        if (tid < st) red[tid] += red[tid + st];
        __syncthreads();
    }
    if (tid == 0) FATOMIC(&norm[b], red[0]);   // sum|y| == sum feat_unnorm^2
}

// ---------------------------------------------------------------------------
// Kernel 4: fused signed-sqrt + L2-normalize + classifier GEMV.
// grid 64: block j owns d in [128j, 128j+128) for all batches.
// ---------------------------------------------------------------------------
__global__ __launch_bounds__(256) void logit_kernel(
    const float* __restrict__ y, const float* __restrict__ norm,
    const float* __restrict__ W, float* __restrict__ out)
{
    const int j = blockIdx.x;
    const int tid = threadIdx.x;
    __shared__ float fs[BATCH][128];                   // 4 KB
    for (int i = tid; i < BATCH * 128; i += 256) {
        int bb = i >> 7, dd = i & 127;
        float v = y[(size_t)bb * DDIM + j * 128 + dd];
        float inv = 1.0f / fmaxf(sqrtf(norm[bb]), 1e-12f);
        float f = copysignf(sqrtf(fabsf(v)), v) * inv;
        fs[bb][dd] = f;
        out[BATCH * NCLS + (size_t)bb * DDIM + j * 128 + dd] = f;
    }
    __syncthreads();
    if (tid < NCLS) {
        float a[BATCH];
#pragma unroll
        for (int bb = 0; bb < BATCH; ++bb) a[bb] = 0.0f;
        for (int dd = 0; dd < 128; ++dd) {
            float w = W[(size_t)(j * 128 + dd) * NCLS + tid];
#pragma unroll
            for (int bb = 0; bb < BATCH; ++bb) a[bb] += fs[bb][dd] * w;
        }
#pragma unroll
        for (int bb = 0; bb < BATCH; ++bb)
            FATOMIC(&out[bb * NCLS + tid], a[bb]);
    }
}

// ---------------------------------------------------------------------------
extern "C" void kernel_launch(void* const* d_in, const int* in_sizes, int n_in,
                              void* d_out, int out_size, void* d_ws, size_t ws_size,
                              hipStream_t stream)
{
    const float* x  = (const float*)d_in[0];
    const float* s1 = (const float*)d_in[1];
    const float* s2 = (const float*)d_in[2];
    const float* W  = (const float*)d_in[3];
    const float* bc = (const float*)d_in[4];
    const int*   h1 = (const int*)d_in[5];
    const int*   h2 = (const int*)d_in[6];
    float* out = (float*)d_out;

    // ws layout: part (17.8MB) | y (256KB) | norm (128B) | xh (26.2MB) ~ 44.3MB
    char* ws = (char*)d_ws;
    float* part = (float*)ws;
    const size_t partbytes = (size_t)NSLOT * BATCH * DDIM * sizeof(float);
    float* y    = (float*)(ws + partbytes);
    const size_t ybytes = (size_t)BATCH * DDIM * sizeof(float);
    float* norm = (float*)(ws + partbytes + ybytes);
    _Float16* xh = (_Float16*)(ws + partbytes + ybytes + 128);

    split_kernel<<<(BATCH * CH * KPAD / 4 + 255) / 256, 256, 0, stream>>>(
        x, xh, norm, bc, out);

    gram_scatter_kernel<<<NSLOT * BATCH, 256, 0, stream>>>(
        xh, h1, s1, h2, s2, part);

    reduce_kernel<<<64, 256, 0, stream>>>(part, y, norm);

    logit_kernel<<<64, 256, 0, stream>>>(y, norm, W, out);
}

// Round 3
// 398.978 us; speedup vs baseline: 1.0134x; 1.0134x over previous
//
#include <hip/hip_runtime.h>
#include <hip/hip_bf16.h>

// Problem constants (ResNet-50 CBP head)
#define BATCH 8
#define CH    2048
#define LSP   784          // H*W = 28*28
#define KPAD  800          // pad K to 25*32 for MFMA k-steps
#define KSTEPS (KPAD/32)   // 25
#define DDIM  8192         // count-sketch dim (power of 2)
#define NCLS  200
#define NTILE 16           // 2048/128 tiles per dim
#define NPAIR 136          // NTILE*(NTILE+1)/2 symmetric tile pairs
#define NSLOT 68           // part slots per batch (2 blocks/slot)

typedef _Float16 f16x8 __attribute__((ext_vector_type(8)));
typedef _Float16 f16x4 __attribute__((ext_vector_type(4)));
typedef float    f32x4 __attribute__((ext_vector_type(4)));

#define FATOMIC(p, v) unsafeAtomicAdd((p), (v))

// ---------------------------------------------------------------------------
// Kernel 1: convert x (fp32 [B,C,784]) to fp16 [B,C,KPAD] (zero-pad K).
// Also: zero part, zero norm, bias-seed logits, and build the packed
// scatter-meta table metaG[c] = (s1[c], h1[c], s2[c], h2[c]) so the gram
// kernel's scatter reads meta via VMEM (vmcnt) instead of LDS (lgkmcnt) --
// lgkmcnt is in-order, so any ds_read between ds_adds drains ALL pending
// atomics (R2 post-mortem: that drain was a per-wave serializer).
// ---------------------------------------------------------------------------
__global__ __launch_bounds__(256) void split_kernel(
    const float* __restrict__ x,
    _Float16* __restrict__ xh,
    float* __restrict__ part, float* __restrict__ norm,
    const float* __restrict__ s1, const int* __restrict__ h1,
    const float* __restrict__ s2, const int* __restrict__ h2,
    float4* __restrict__ metaG,
    const float* __restrict__ bc, float* __restrict__ out)
{
    int idx = blockIdx.x * 256 + threadIdx.x;          // vec4 index
    if (idx < NSLOT * BATCH * DDIM / 4)                // zero part (float4)
        *(float4*)&part[idx * 4] = make_float4(0.f, 0.f, 0.f, 0.f);
    if (idx < CH)
        metaG[idx] = make_float4(s1[idx], __int_as_float(h1[idx]),
                                 s2[idx], __int_as_float(h2[idx]));
    if (idx < BATCH) norm[idx] = 0.0f;
    if (idx < BATCH * NCLS) out[idx] = bc[idx % NCLS]; // bias-seed logits
    if (idx >= BATCH * CH * KPAD / 4) return;
    int v  = idx * 4;
    int bc_ = v / KPAD;
    int l  = v - bc_ * KPAD;                           // multiple of 4
    float4 xv = make_float4(0.f, 0.f, 0.f, 0.f);
    if (l < LSP)                                       // LSP%4==0: uniform per vec
        xv = *(const float4*)&x[(size_t)bc_ * LSP + l];
    f16x4 hv;
    hv[0] = (_Float16)xv.x; hv[1] = (_Float16)xv.y;
    hv[2] = (_Float16)xv.z; hv[3] = (_Float16)xv.w;
    *(f16x4*)&xh[v] = hv;
}

// ---------------------------------------------------------------------------
// Kernel 2: symmetric Gram tile (fp16 MFMA, fragments direct from global)
// + count-sketch scatter into an LDS histogram.
// R3 theory: the kernel is DS-pipe-bound (33.5M conflicting LDS atomic RMWs;
// invisible in all rocprof counters). Two levers, op count unchanged:
//  (1) zero lgkmcnt-ordered reads inside the scatter (meta via VMEM),
//  (2) 4 blocks/CU co-resident (bins-only 32 KB LDS, launch_bounds(256,4),
//      1088 one-pair blocks) so de-phased blocks keep the DS pipe saturated
//      while others run k-loops on VMEM/MFMA (R0>R1/R2 showed this scaling).
// grid = 1088: batch = id&7 (one batch per XCD, 3.3 MB L2 set), pair = id>>3.
// ---------------------------------------------------------------------------
__global__ __launch_bounds__(256, 4) void gram_scatter_kernel(
    const _Float16* __restrict__ xh,
    const float4* __restrict__ metaG,
    float* __restrict__ part)
{
    __shared__ float bins[DDIM];                             // 32 KB (only LDS)

    const int tid  = threadIdx.x;
    const int lane = tid & 63;
    const int wv   = tid >> 6;
    const int b    = blockIdx.x & 7;       // batch in low bits -> one batch/XCD
    const int pidx = blockIdx.x >> 3;      // triangular pair index

    for (int i = tid; i < DDIM; i += 256) bins[i] = 0.0f;

    // Triangular decode: pidx in [0,136) -> (tM, tN), tM <= tN, row-major
    int tM = 0, tN = 0;
    {
        int i = pidx;
#pragma unroll 1
        for (int t = 0; t < NTILE; ++t) {
            int cnt = NTILE - t;
            if (i < cnt) { tM = t; tN = t + i; break; }
            i -= cnt;
        }
    }
    const bool diag = (tM == tN);

    const int wrow = (wv >> 1) * 64;    // wave's 64x64 subtile origin
    const int wcol = (wv & 1) * 64;
    const int rsel = lane & 15;
    const int klane = (lane >> 4) * 8;  // k element offset within a k-step

    // MFMA fragment addresses, straight from global (L2-resident):
    // A frag: row = tM*128 + wrow + i*16 + (lane&15), k = k0 + (lane>>4)*8
    // (same element->lane mapping as the LDS path: numerics unchanged)
    const _Float16* baseA = xh + ((size_t)b * CH + (size_t)tM * 128) * KPAD + klane;
    const _Float16* baseB = xh + ((size_t)b * CH + (size_t)tN * 128) * KPAD + klane;
    const _Float16* pa[4];
    const _Float16* pb[4];
#pragma unroll
    for (int i = 0; i < 4; ++i) {
        pa[i] = baseA + (size_t)(wrow + i * 16 + rsel) * KPAD;
        pb[i] = baseB + (size_t)(wcol + i * 16 + rsel) * KPAD;
    }

    f32x4 acc[4][4];
    const f32x4 zv = {0.0f, 0.0f, 0.0f, 0.0f};
#pragma unroll
    for (int mi = 0; mi < 4; ++mi)
#pragma unroll
        for (int ni = 0; ni < 4; ++ni) acc[mi][ni] = zv;

    // Pure register k-loop: 8 x global_load_dwordx4 + 16 MFMA per step,
    // no barriers, no LDS. unroll 5 gives the scheduler a pipeline window.
#pragma unroll 5
    for (int s = 0; s < KSTEPS; ++s) {
        f16x8 ah[4], bh[4];
#pragma unroll
        for (int i = 0; i < 4; ++i) {
            ah[i] = *(const f16x8*)(pa[i] + s * 32);
            bh[i] = *(const f16x8*)(pb[i] + s * 32);
        }
#pragma unroll
        for (int mi = 0; mi < 4; ++mi)
#pragma unroll
            for (int ni = 0; ni < 4; ++ni)
                acc[mi][ni] = __builtin_amdgcn_mfma_f32_16x16x32_f16(ah[mi], bh[ni], acc[mi][ni], 0, 0, 0);
    }

    __syncthreads();   // bins zero-init complete before first ds_add

    // Column meta: one packed float4 per c2 (VMEM, L2-hot).
    const int c2b = tN * 128 + wcol + rsel;
    int   h1c[4], h2c[4]; float s1c[4], s2c[4];
#pragma unroll
    for (int ni = 0; ni < 4; ++ni) {
        float4 cm = metaG[c2b + ni * 16];
        s1c[ni] = cm.x; h1c[ni] = __float_as_int(cm.y);
        s2c[ni] = cm.z; h2c[ni] = __float_as_int(cm.w);
    }

    // Scatter the 128x128 Gram tile into the LDS histogram.
    // C/D layout (m89-verified): col = lane&15, row = (lane>>4)*4 + reg
    // Row meta also via VMEM (broadcast across 16-lane groups) -> the ds_add
    // stream below has NO interleaved lgkmcnt-ordered ops: fire-and-forget.
    const int rowbase = tM * 128 + wrow + ((lane >> 4) << 2);
#pragma unroll
    for (int mi = 0; mi < 4; ++mi) {
        float4 rm[4];
#pragma unroll
        for (int r = 0; r < 4; ++r) rm[r] = metaG[rowbase + mi * 16 + r];
#pragma unroll
        for (int r = 0; r < 4; ++r) {
            const float s1r = rm[r].x, s2r = rm[r].z;
            const int h1r = __float_as_int(rm[r].y);
            const int h2r = __float_as_int(rm[r].w);
#pragma unroll
            for (int ni = 0; ni < 4; ++ni) {
                float g = acc[mi][ni][r];
                FATOMIC(&bins[(h1r + h2c[ni]) & (DDIM - 1)], s1r * s2c[ni] * g);
                if (!diag)
                    FATOMIC(&bins[(h1c[ni] + h2r) & (DDIM - 1)], s1c[ni] * s2r * g);
            }
        }
    }

    __syncthreads();   // all scatters into bins complete

    // Flush to one of 68 part slots (2 blocks/slot -> near-uncontended),
    // rotated start per block to decontend cache lines (R0-proven).
    float* pbase = part + ((size_t)((pidx % NSLOT) * BATCH + b) * DDIM);
    const int rot = (blockIdx.x & 31) << 8;
    for (int i = tid; i < DDIM; i += 256) {
        int j = (i + rot) & (DDIM - 1);
        float v = bins[j];
        if (v != 0.0f) FATOMIC(&pbase[j], v);
    }
}

// ---------------------------------------------------------------------------
// Kernel 3: y[b,d] = sum over 68 part slots; accumulate norm[b] += sum|y|.
// grid 64 x 256: one float4 of d per thread. batch = blockIdx&7 so each
// batch's reduce blocks land on the XCD whose L2 holds that batch's part
// lines (written by the gram blocks with the same &7 mapping).
// NOTE: this kernel overwrites y, whose first 32 KB doubled as metaG for
// the (already finished) gram kernel -- intentional workspace reuse.
// ---------------------------------------------------------------------------
__global__ __launch_bounds__(256) void reduce_kernel(
    const float* __restrict__ part, float* __restrict__ y,
    float* __restrict__ norm)
{
    const int tid = threadIdx.x;
    const int b  = blockIdx.x & 7;
    const int d0 = (((blockIdx.x >> 3) * 256) + tid) * 4;  // float4 slice
    float4 s = make_float4(0.f, 0.f, 0.f, 0.f);
#pragma unroll 4
    for (int p = 0; p < NSLOT; ++p) {
        float4 v = *(const float4*)&part[((size_t)p * BATCH + b) * DDIM + d0];
        s.x += v.x; s.y += v.y; s.z += v.z; s.w += v.w;
    }
    *(float4*)&y[(size_t)b * DDIM + d0] = s;
    float ab = fabsf(s.x) + fabsf(s.y) + fabsf(s.z) + fabsf(s.w);
    __shared__ float red[256];
    red[tid] = ab;
    __syncthreads();
    for (int st = 128; st > 0; st >>= 1) {
        if (tid < st) red[tid] += red[tid + st];
        __syncthreads();
    }
    if (tid == 0) FATOMIC(&norm[b], red[0]);   // sum|y| == sum feat_unnorm^2
}

// ---------------------------------------------------------------------------
// Kernel 4: fused signed-sqrt + L2-normalize + classifier GEMV.
// grid 64: block j owns d in [128j, 128j+128) for all batches.
// ---------------------------------------------------------------------------
__global__ __launch_bounds__(256) void logit_kernel(
    const float* __restrict__ y, const float* __restrict__ norm,
    const float* __restrict__ W, float* __restrict__ out)
{
    const int j = blockIdx.x;
    const int tid = threadIdx.x;
    __shared__ float fs[BATCH][128];                   // 4 KB
    for (int i = tid; i < BATCH * 128; i += 256) {
        int bb = i >> 7, dd = i & 127;
        float v = y[(size_t)bb * DDIM + j * 128 + dd];
        float inv = 1.0f / fmaxf(sqrtf(norm[bb]), 1e-12f);
        float f = copysignf(sqrtf(fabsf(v)), v) * inv;
        fs[bb][dd] = f;
        out[BATCH * NCLS + (size_t)bb * DDIM + j * 128 + dd] = f;
    }
    __syncthreads();
    if (tid < NCLS) {
        float a[BATCH];
#pragma unroll
        for (int bb = 0; bb < BATCH; ++bb) a[bb] = 0.0f;
        for (int dd = 0; dd < 128; ++dd) {
            float w = W[(size_t)(j * 128 + dd) * NCLS + tid];
#pragma unroll
            for (int bb = 0; bb < BATCH; ++bb) a[bb] += fs[bb][dd] * w;
        }
#pragma unroll
        for (int bb = 0; bb < BATCH; ++bb)
            FATOMIC(&out[bb * NCLS + tid], a[bb]);
    }
}

// ---------------------------------------------------------------------------
extern "C" void kernel_launch(void* const* d_in, const int* in_sizes, int n_in,
                              void* d_out, int out_size, void* d_ws, size_t ws_size,
                              hipStream_t stream)
{
    const float* x  = (const float*)d_in[0];
    const float* s1 = (const float*)d_in[1];
    const float* s2 = (const float*)d_in[2];
    const float* W  = (const float*)d_in[3];
    const float* bc = (const float*)d_in[4];
    const int*   h1 = (const int*)d_in[5];
    const int*   h2 = (const int*)d_in[6];
    float* out = (float*)d_out;

    // ws layout: part (17.8MB) | y (256KB; first 32KB doubles as metaG before
    // reduce overwrites it) | norm (128B) | xh (26.2MB)  ~ 44.3MB total
    char* ws = (char*)d_ws;
    float* part = (float*)ws;
    const size_t partbytes = (size_t)NSLOT * BATCH * DDIM * sizeof(float);
    float* y    = (float*)(ws + partbytes);
    float4* metaG = (float4*)(ws + partbytes);         // overlay on y region
    const size_t ybytes = (size_t)BATCH * DDIM * sizeof(float);
    float* norm = (float*)(ws + partbytes + ybytes);
    _Float16* xh = (_Float16*)(ws + partbytes + ybytes + 128);

    split_kernel<<<(BATCH * CH * KPAD / 4 + 255) / 256, 256, 0, stream>>>(
        x, xh, part, norm, s1, h1, s2, h2, metaG, bc, out);

    gram_scatter_kernel<<<NPAIR * BATCH, 256, 0, stream>>>(
        xh, metaG, part);

    reduce_kernel<<<64, 256, 0, stream>>>(part, y, norm);

    logit_kernel<<<64, 256, 0, stream>>>(y, norm, W, out);
}

// Round 4
// 230.448 us; speedup vs baseline: 1.7545x; 1.7313x over previous
//
#include <hip/hip_runtime.h>
#include <hip/hip_bf16.h>

// Problem constants (ResNet-50 CBP head)
#define BATCH 8
#define CH    2048
#define LSP   784          // H*W = 28*28
#define KPAD  800          // pad K to 25*32 for MFMA k-steps
#define KSTEPS (KPAD/32)   // 25
#define DDIM  8192         // count-sketch dim (power of 2)
#define NCLS  200
#define NTILE 16           // 2048/128 tiles per dim
#define NPAIR 136          // NTILE*(NTILE+1)/2 symmetric tile pairs
#define NSLOT 68           // part slots per batch (2 blocks/slot)
#define FXSCALE 8192.0f    // fixed-point scale 2^13 (split as 64*128 into meta)
#define FXINV   (1.0f/8192.0f)

typedef _Float16 f16x8 __attribute__((ext_vector_type(8)));
typedef _Float16 f16x4 __attribute__((ext_vector_type(4)));
typedef float    f32x4 __attribute__((ext_vector_type(4)));

#define FATOMIC(p, v) unsafeAtomicAdd((p), (v))

// ---------------------------------------------------------------------------
// Kernel 1: convert x (fp32 [B,C,784]) to fp16 [B,C,KPAD] (zero-pad K).
// Also: zero part, zero norm, bias-seed logits, and build the packed
// scatter-meta table metaG[c] = (s1[c]*64, h1[c], s2[c]*128, h2[c]).
// The 64*128 = 8192 = 2^13 fixed-point scale rides along the s1*s2 product,
// so the gram scatter's contribution is already scaled for int conversion.
// ---------------------------------------------------------------------------
__global__ __launch_bounds__(256) void split_kernel(
    const float* __restrict__ x,
    _Float16* __restrict__ xh,
    float* __restrict__ part, float* __restrict__ norm,
    const float* __restrict__ s1, const int* __restrict__ h1,
    const float* __restrict__ s2, const int* __restrict__ h2,
    float4* __restrict__ metaG,
    const float* __restrict__ bc, float* __restrict__ out)
{
    int idx = blockIdx.x * 256 + threadIdx.x;          // vec4 index
    if (idx < NSLOT * BATCH * DDIM / 4)                // zero part (float4)
        *(float4*)&part[idx * 4] = make_float4(0.f, 0.f, 0.f, 0.f);
    if (idx < CH)
        metaG[idx] = make_float4(s1[idx] * 64.0f, __int_as_float(h1[idx]),
                                 s2[idx] * 128.0f, __int_as_float(h2[idx]));
    if (idx < BATCH) norm[idx] = 0.0f;
    if (idx < BATCH * NCLS) out[idx] = bc[idx % NCLS]; // bias-seed logits
    if (idx >= BATCH * CH * KPAD / 4) return;
    int v  = idx * 4;
    int bc_ = v / KPAD;
    int l  = v - bc_ * KPAD;                           // multiple of 4
    float4 xv = make_float4(0.f, 0.f, 0.f, 0.f);
    if (l < LSP)                                       // LSP%4==0: uniform per vec
        xv = *(const float4*)&x[(size_t)bc_ * LSP + l];
    f16x4 hv;
    hv[0] = (_Float16)xv.x; hv[1] = (_Float16)xv.y;
    hv[2] = (_Float16)xv.z; hv[3] = (_Float16)xv.w;
    *(f16x4*)&xh[v] = hv;
}

// ---------------------------------------------------------------------------
// Kernel 2: symmetric Gram tile (fp16 MFMA, fragments direct from global)
// + count-sketch scatter into an INT32 LDS histogram.
// R4 theory: R0-R3 all bottleneck at ~4.5 cyc per ds_add_f32 lane (invariant
// across staging scheme, meta path, flush path, occupancy; and
// SQ_LDS_BANK_CONFLICT==0 shows atomics bypass the banked path) -> the LDS
// FP32 atomic unit is a slow serial resource. Fix: int32 fixed-point bins
// via ds_add_u32 (banked integer RMW). Scale 2^13 folded into meta (64*128);
// quantization noise ~1e-4 on y vs existing fp16-Gram noise ~0.9 -> free.
// Everything else identical to R3.
// grid = 1088: batch = id&7 (one batch per XCD, 3.3 MB L2 set), pair = id>>3.
// ---------------------------------------------------------------------------
__global__ __launch_bounds__(256, 4) void gram_scatter_kernel(
    const _Float16* __restrict__ xh,
    const float4* __restrict__ metaG,
    float* __restrict__ part)
{
    __shared__ int bins[DDIM];                               // 32 KB (only LDS)

    const int tid  = threadIdx.x;
    const int lane = tid & 63;
    const int wv   = tid >> 6;
    const int b    = blockIdx.x & 7;       // batch in low bits -> one batch/XCD
    const int pidx = blockIdx.x >> 3;      // triangular pair index

    for (int i = tid; i < DDIM; i += 256) bins[i] = 0;

    // Triangular decode: pidx in [0,136) -> (tM, tN), tM <= tN, row-major
    int tM = 0, tN = 0;
    {
        int i = pidx;
#pragma unroll 1
        for (int t = 0; t < NTILE; ++t) {
            int cnt = NTILE - t;
            if (i < cnt) { tM = t; tN = t + i; break; }
            i -= cnt;
        }
    }
    const bool diag = (tM == tN);

    const int wrow = (wv >> 1) * 64;    // wave's 64x64 subtile origin
    const int wcol = (wv & 1) * 64;
    const int rsel = lane & 15;
    const int klane = (lane >> 4) * 8;  // k element offset within a k-step

    // MFMA fragment addresses, straight from global (L2-resident):
    // A frag: row = tM*128 + wrow + i*16 + (lane&15), k = k0 + (lane>>4)*8
    // (same element->lane mapping as the LDS path: numerics unchanged)
    const _Float16* baseA = xh + ((size_t)b * CH + (size_t)tM * 128) * KPAD + klane;
    const _Float16* baseB = xh + ((size_t)b * CH + (size_t)tN * 128) * KPAD + klane;
    const _Float16* pa[4];
    const _Float16* pb[4];
#pragma unroll
    for (int i = 0; i < 4; ++i) {
        pa[i] = baseA + (size_t)(wrow + i * 16 + rsel) * KPAD;
        pb[i] = baseB + (size_t)(wcol + i * 16 + rsel) * KPAD;
    }

    f32x4 acc[4][4];
    const f32x4 zv = {0.0f, 0.0f, 0.0f, 0.0f};
#pragma unroll
    for (int mi = 0; mi < 4; ++mi)
#pragma unroll
        for (int ni = 0; ni < 4; ++ni) acc[mi][ni] = zv;

    // Pure register k-loop: 8 x global_load_dwordx4 + 16 MFMA per step,
    // no barriers, no LDS. unroll 5 gives the scheduler a pipeline window.
#pragma unroll 5
    for (int s = 0; s < KSTEPS; ++s) {
        f16x8 ah[4], bh[4];
#pragma unroll
        for (int i = 0; i < 4; ++i) {
            ah[i] = *(const f16x8*)(pa[i] + s * 32);
            bh[i] = *(const f16x8*)(pb[i] + s * 32);
        }
#pragma unroll
        for (int mi = 0; mi < 4; ++mi)
#pragma unroll
            for (int ni = 0; ni < 4; ++ni)
                acc[mi][ni] = __builtin_amdgcn_mfma_f32_16x16x32_f16(ah[mi], bh[ni], acc[mi][ni], 0, 0, 0);
    }

    __syncthreads();   // bins zero-init complete before first ds_add

    // Column meta: one packed float4 per c2 (VMEM, L2-hot). s-values carry
    // the fixed-point scale (s1*64, s2*128).
    const int c2b = tN * 128 + wcol + rsel;
    int   h1c[4], h2c[4]; float s1c[4], s2c[4];
#pragma unroll
    for (int ni = 0; ni < 4; ++ni) {
        float4 cm = metaG[c2b + ni * 16];
        s1c[ni] = cm.x; h1c[ni] = __float_as_int(cm.y);
        s2c[ni] = cm.z; h2c[ni] = __float_as_int(cm.w);
    }

    // Scatter the 128x128 Gram tile into the LDS int histogram.
    // C/D layout (m89-verified): col = lane&15, row = (lane>>4)*4 + reg
    // Row meta also via VMEM -> zero lgkmcnt-ordered ops between ds_adds.
    // Contribution = s1*s2*g*2^13, truncated to int: ds_add_u32 (banked).
    const int rowbase = tM * 128 + wrow + ((lane >> 4) << 2);
#pragma unroll
    for (int mi = 0; mi < 4; ++mi) {
        float4 rm[4];
#pragma unroll
        for (int r = 0; r < 4; ++r) rm[r] = metaG[rowbase + mi * 16 + r];
#pragma unroll
        for (int r = 0; r < 4; ++r) {
            const float s1r = rm[r].x, s2r = rm[r].z;
            const int h1r = __float_as_int(rm[r].y);
            const int h2r = __float_as_int(rm[r].w);
#pragma unroll
            for (int ni = 0; ni < 4; ++ni) {
                float g = acc[mi][ni][r];
                atomicAdd(&bins[(h1r + h2c[ni]) & (DDIM - 1)],
                          (int)(s1r * s2c[ni] * g));
                if (!diag)
                    atomicAdd(&bins[(h1c[ni] + h2r) & (DDIM - 1)],
                              (int)(s1c[ni] * s2r * g));
            }
        }
    }

    __syncthreads();   // all scatters into bins complete

    // Flush to one of 68 part slots (2 blocks/slot -> near-uncontended),
    // rotated start per block to decontend cache lines. Convert back to
    // float (int32->f32 exact to 2^-24 rel; values < 2^25 here).
    float* pbase = part + ((size_t)((pidx % NSLOT) * BATCH + b) * DDIM);
    const int rot = (blockIdx.x & 31) << 8;
    for (int i = tid; i < DDIM; i += 256) {
        int j = (i + rot) & (DDIM - 1);
        int v = bins[j];
        if (v != 0) FATOMIC(&pbase[j], (float)v * FXINV);
    }
}

// ---------------------------------------------------------------------------
// Kernel 3: y[b,d] = sum over 68 part slots; accumulate norm[b] += sum|y|.
// grid 64 x 256: one float4 of d per thread. batch = blockIdx&7 so each
// batch's reduce blocks land on the XCD whose L2 holds that batch's part
// lines (written by the gram blocks with the same &7 mapping).
// NOTE: this kernel overwrites y, whose first 32 KB doubled as metaG for
// the (already finished) gram kernel -- intentional workspace reuse.
// ---------------------------------------------------------------------------
__global__ __launch_bounds__(256) void reduce_kernel(
    const float* __restrict__ part, float* __restrict__ y,
    float* __restrict__ norm)
{
    const int tid = threadIdx.x;
    const int b  = blockIdx.x & 7;
    const int d0 = (((blockIdx.x >> 3) * 256) + tid) * 4;  // float4 slice
    float4 s = make_float4(0.f, 0.f, 0.f, 0.f);
#pragma unroll 4
    for (int p = 0; p < NSLOT; ++p) {
        float4 v = *(const float4*)&part[((size_t)p * BATCH + b) * DDIM + d0];
        s.x += v.x; s.y += v.y; s.z += v.z; s.w += v.w;
    }
    *(float4*)&y[(size_t)b * DDIM + d0] = s;
    float ab = fabsf(s.x) + fabsf(s.y) + fabsf(s.z) + fabsf(s.w);
    __shared__ float red[256];
    red[tid] = ab;
    __syncthreads();
    for (int st = 128; st > 0; st >>= 1) {
        if (tid < st) red[tid] += red[tid + st];
        __syncthreads();
    }
    if (tid == 0) FATOMIC(&norm[b], red[0]);   // sum|y| == sum feat_unnorm^2
}

// ---------------------------------------------------------------------------
// Kernel 4: fused signed-sqrt + L2-normalize + classifier GEMV.
// grid 64: block j owns d in [128j, 128j+128) for all batches.
// ---------------------------------------------------------------------------
__global__ __launch_bounds__(256) void logit_kernel(
    const float* __restrict__ y, const float* __restrict__ norm,
    const float* __restrict__ W, float* __restrict__ out)
{
    const int j = blockIdx.x;
    const int tid = threadIdx.x;
    __shared__ float fs[BATCH][128];                   // 4 KB
    for (int i = tid; i < BATCH * 128; i += 256) {
        int bb = i >> 7, dd = i & 127;
        float v = y[(size_t)bb * DDIM + j * 128 + dd];
        float inv = 1.0f / fmaxf(sqrtf(norm[bb]), 1e-12f);
        float f = copysignf(sqrtf(fabsf(v)), v) * inv;
        fs[bb][dd] = f;
        out[BATCH * NCLS + (size_t)bb * DDIM + j * 128 + dd] = f;
    }
    __syncthreads();
    if (tid < NCLS) {
        float a[BATCH];
#pragma unroll
        for (int bb = 0; bb < BATCH; ++bb) a[bb] = 0.0f;
        for (int dd = 0; dd < 128; ++dd) {
            float w = W[(size_t)(j * 128 + dd) * NCLS + tid];
#pragma unroll
            for (int bb = 0; bb < BATCH; ++bb) a[bb] += fs[bb][dd] * w;
        }
#pragma unroll
        for (int bb = 0; bb < BATCH; ++bb)
            FATOMIC(&out[bb * NCLS + tid], a[bb]);
    }
}

// ---------------------------------------------------------------------------
extern "C" void kernel_launch(void* const* d_in, const int* in_sizes, int n_in,
                              void* d_out, int out_size, void* d_ws, size_t ws_size,
                              hipStream_t stream)
{
    const float* x  = (const float*)d_in[0];
    const float* s1 = (const float*)d_in[1];
    const float* s2 = (const float*)d_in[2];
    const float* W  = (const float*)d_in[3];
    const float* bc = (const float*)d_in[4];
    const int*   h1 = (const int*)d_in[5];
    const int*   h2 = (const int*)d_in[6];
    float* out = (float*)d_out;

    // ws layout: part (17.8MB) | y (256KB; first 32KB doubles as metaG before
    // reduce overwrites it) | norm (128B) | xh (26.2MB)  ~ 44.3MB total
    char* ws = (char*)d_ws;
    float* part = (float*)ws;
    const size_t partbytes = (size_t)NSLOT * BATCH * DDIM * sizeof(float);
    float* y    = (float*)(ws + partbytes);
    float4* metaG = (float4*)(ws + partbytes);         // overlay on y region
    const size_t ybytes = (size_t)BATCH * DDIM * sizeof(float);
    float* norm = (float*)(ws + partbytes + ybytes);
    _Float16* xh = (_Float16*)(ws + partbytes + ybytes + 128);

    split_kernel<<<(BATCH * CH * KPAD / 4 + 255) / 256, 256, 0, stream>>>(
        x, xh, part, norm, s1, h1, s2, h2, metaG, bc, out);

    gram_scatter_kernel<<<NPAIR * BATCH, 256, 0, stream>>>(
        xh, metaG, part);

    reduce_kernel<<<64, 256, 0, stream>>>(part, y, norm);

    logit_kernel<<<64, 256, 0, stream>>>(y, norm, W, out);
}

// Round 5
// 221.592 us; speedup vs baseline: 1.8246x; 1.0400x over previous
//
#include <hip/hip_runtime.h>
#include <hip/hip_bf16.h>

// Problem constants (ResNet-50 CBP head)
#define BATCH 8
#define CH    2048
#define LSP   784          // H*W = 28*28
#define KPAD  800          // pad K to 25*32 for MFMA k-steps
#define KSTEPS (KPAD/32)   // 25
#define DDIM  8192         // count-sketch dim (power of 2)
#define NCLS  200
#define NTILE 16           // 2048/128 tiles per dim
#define NPAIR 136          // NTILE*(NTILE+1)/2 symmetric tile pairs
#define NSLOT 68           // fallback: part slots per batch (2 blocks/slot)
#define FXSCALE 8192.0f    // fixed-point scale 2^13 (split as 64*128 into meta)
#define FXINV   (1.0f/8192.0f)

typedef _Float16 f16x8 __attribute__((ext_vector_type(8)));
typedef _Float16 f16x4 __attribute__((ext_vector_type(4)));
typedef float    f32x4 __attribute__((ext_vector_type(4)));

#define FATOMIC(p, v) unsafeAtomicAdd((p), (v))

// ---------------------------------------------------------------------------
// Kernel 1: convert x (fp32 [B,C,784]) to fp16 [B,C,KPAD] (zero-pad K).
// Also: zero norm, bias-seed logits, build the packed scatter-meta table
// metaG[c] = (s1[c]*64, h1[c], s2[c]*128, h2[c]) (2^13 fixed-point scale
// rides the s1*s2 product), and -- ONLY in atomic-fallback mode -- zero part.
// In exclusive mode every part slot is fully overwritten by plain stores.
// ---------------------------------------------------------------------------
__global__ __launch_bounds__(256) void split_kernel(
    const float* __restrict__ x,
    _Float16* __restrict__ xh,
    float* __restrict__ part, float* __restrict__ norm,
    const float* __restrict__ s1, const int* __restrict__ h1,
    const float* __restrict__ s2, const int* __restrict__ h2,
    float4* __restrict__ metaG,
    const float* __restrict__ bc, float* __restrict__ out,
    int exclusive)
{
    int idx = blockIdx.x * 256 + threadIdx.x;          // vec4 index
    if (!exclusive && idx < NSLOT * BATCH * DDIM / 4)  // zero part (fallback)
        *(float4*)&part[idx * 4] = make_float4(0.f, 0.f, 0.f, 0.f);
    if (idx < CH)
        metaG[idx] = make_float4(s1[idx] * 64.0f, __int_as_float(h1[idx]),
                                 s2[idx] * 128.0f, __int_as_float(h2[idx]));
    if (idx < BATCH) norm[idx] = 0.0f;
    if (idx < BATCH * NCLS) out[idx] = bc[idx % NCLS]; // bias-seed logits
    if (idx >= BATCH * CH * KPAD / 4) return;
    int v  = idx * 4;
    int bc_ = v / KPAD;
    int l  = v - bc_ * KPAD;                           // multiple of 4
    float4 xv = make_float4(0.f, 0.f, 0.f, 0.f);
    if (l < LSP)                                       // LSP%4==0: uniform per vec
        xv = *(const float4*)&x[(size_t)bc_ * LSP + l];
    f16x4 hv;
    hv[0] = (_Float16)xv.x; hv[1] = (_Float16)xv.y;
    hv[2] = (_Float16)xv.z; hv[3] = (_Float16)xv.w;
    *(f16x4*)&xh[v] = hv;
}

// ---------------------------------------------------------------------------
// Kernel 2: symmetric Gram tile (fp16 MFMA, fragments direct from global)
// + count-sketch scatter into an INT32 LDS histogram (R4-proven: banked
// ds_add_u32, not the slow FP LDS-atomic unit).
// R5 theory: the remaining serial resource was the FLUSH -- 8.9M device-scope
// fp32 global atomics write through to HBM (R4: WRITE_SIZE == 1088x32KB
// exactly, hbm_gbps pinned at ~430 GB/s => ~83us of the 115us). Fix: every
// block gets an EXCLUSIVE part slot (136 slots x 8 batches == grid), flush is
// plain coalesced float4 stores through L2. Runtime fallback to the R4
// 68-slot atomic flush if ws_size can't hold the 34MB part.
// grid = 1088: batch = id&7 (one batch per XCD, 3.3 MB L2 set), pair = id>>3.
// ---------------------------------------------------------------------------
__global__ __launch_bounds__(256, 4) void gram_scatter_kernel(
    const _Float16* __restrict__ xh,
    const float4* __restrict__ metaG,
    float* __restrict__ part,
    int exclusive)
{
    __shared__ __align__(16) int bins[DDIM];                 // 32 KB (only LDS)

    const int tid  = threadIdx.x;
    const int lane = tid & 63;
    const int wv   = tid >> 6;
    const int b    = blockIdx.x & 7;       // batch in low bits -> one batch/XCD
    const int pidx = blockIdx.x >> 3;      // triangular pair index

    for (int i = tid; i < DDIM; i += 256) bins[i] = 0;

    // Triangular decode: pidx in [0,136) -> (tM, tN), tM <= tN, row-major
    int tM = 0, tN = 0;
    {
        int i = pidx;
#pragma unroll 1
        for (int t = 0; t < NTILE; ++t) {
            int cnt = NTILE - t;
            if (i < cnt) { tM = t; tN = t + i; break; }
            i -= cnt;
        }
    }
    const bool diag = (tM == tN);

    const int wrow = (wv >> 1) * 64;    // wave's 64x64 subtile origin
    const int wcol = (wv & 1) * 64;
    const int rsel = lane & 15;
    const int klane = (lane >> 4) * 8;  // k element offset within a k-step

    // MFMA fragment addresses, straight from global (L2-resident):
    // A frag: row = tM*128 + wrow + i*16 + (lane&15), k = k0 + (lane>>4)*8
    const _Float16* baseA = xh + ((size_t)b * CH + (size_t)tM * 128) * KPAD + klane;
    const _Float16* baseB = xh + ((size_t)b * CH + (size_t)tN * 128) * KPAD + klane;
    const _Float16* pa[4];
    const _Float16* pb[4];
#pragma unroll
    for (int i = 0; i < 4; ++i) {
        pa[i] = baseA + (size_t)(wrow + i * 16 + rsel) * KPAD;
        pb[i] = baseB + (size_t)(wcol + i * 16 + rsel) * KPAD;
    }

    f32x4 acc[4][4];
    const f32x4 zv = {0.0f, 0.0f, 0.0f, 0.0f};
#pragma unroll
    for (int mi = 0; mi < 4; ++mi)
#pragma unroll
        for (int ni = 0; ni < 4; ++ni) acc[mi][ni] = zv;

    // Pure register k-loop: 8 x global_load_dwordx4 + 16 MFMA per step,
    // no barriers, no LDS. unroll 5 gives the scheduler a pipeline window.
#pragma unroll 5
    for (int s = 0; s < KSTEPS; ++s) {
        f16x8 ah[4], bh[4];
#pragma unroll
        for (int i = 0; i < 4; ++i) {
            ah[i] = *(const f16x8*)(pa[i] + s * 32);
            bh[i] = *(const f16x8*)(pb[i] + s * 32);
        }
#pragma unroll
        for (int mi = 0; mi < 4; ++mi)
#pragma unroll
            for (int ni = 0; ni < 4; ++ni)
                acc[mi][ni] = __builtin_amdgcn_mfma_f32_16x16x32_f16(ah[mi], bh[ni], acc[mi][ni], 0, 0, 0);
    }

    __syncthreads();   // bins zero-init complete before first ds_add

    // Column meta: one packed float4 per c2 (VMEM, L2-hot). s-values carry
    // the fixed-point scale (s1*64, s2*128).
    const int c2b = tN * 128 + wcol + rsel;
    int   h1c[4], h2c[4]; float s1c[4], s2c[4];
#pragma unroll
    for (int ni = 0; ni < 4; ++ni) {
        float4 cm = metaG[c2b + ni * 16];
        s1c[ni] = cm.x; h1c[ni] = __float_as_int(cm.y);
        s2c[ni] = cm.z; h2c[ni] = __float_as_int(cm.w);
    }

    // Scatter the 128x128 Gram tile into the LDS int histogram.
    // C/D layout (m89-verified): col = lane&15, row = (lane>>4)*4 + reg
    // Row meta also via VMEM -> zero lgkmcnt-ordered ops between ds_adds.
    const int rowbase = tM * 128 + wrow + ((lane >> 4) << 2);
#pragma unroll
    for (int mi = 0; mi < 4; ++mi) {
        float4 rm[4];
#pragma unroll
        for (int r = 0; r < 4; ++r) rm[r] = metaG[rowbase + mi * 16 + r];
#pragma unroll
        for (int r = 0; r < 4; ++r) {
            const float s1r = rm[r].x, s2r = rm[r].z;
            const int h1r = __float_as_int(rm[r].y);
            const int h2r = __float_as_int(rm[r].w);
#pragma unroll
            for (int ni = 0; ni < 4; ++ni) {
                float g = acc[mi][ni][r];
                atomicAdd(&bins[(h1r + h2c[ni]) & (DDIM - 1)],
                          (int)(s1r * s2c[ni] * g));
                if (!diag)
                    atomicAdd(&bins[(h1c[ni] + h2r) & (DDIM - 1)],
                              (int)(s1c[ni] * s2r * g));
            }
        }
    }

    __syncthreads();   // all scatters into bins complete

    if (exclusive) {
        // Exclusive slot: plain coalesced float4 stores through L2.
        float* pbase = part + ((size_t)(pidx * BATCH + b) * DDIM);
#pragma unroll 4
        for (int i = tid; i < DDIM / 4; i += 256) {
            int4 v = *(const int4*)&bins[i * 4];
            float4 f = make_float4((float)v.x * FXINV, (float)v.y * FXINV,
                                   (float)v.z * FXINV, (float)v.w * FXINV);
            *(float4*)&pbase[i * 4] = f;
        }
    } else {
        // Fallback: 68 shared slots, fp32 global atomics, rotated start.
        float* pbase = part + ((size_t)((pidx % NSLOT) * BATCH + b) * DDIM);
        const int rot = (blockIdx.x & 31) << 8;
        for (int i = tid; i < DDIM; i += 256) {
            int j = (i + rot) & (DDIM - 1);
            int v = bins[j];
            if (v != 0) FATOMIC(&pbase[j], (float)v * FXINV);
        }
    }
}

// ---------------------------------------------------------------------------
// Kernel 3: y[b,d] = sum over nslots part slots; norm[b] += sum|y|.
// grid 64 x 256: one float4 of d per thread. batch = blockIdx&7 keeps each
// batch's reads on the XCD whose L2 holds that batch's freshly-written part.
// NOTE: overwrites y, whose first 32 KB doubled as metaG for the (already
// finished) gram kernel -- intentional workspace reuse.
// ---------------------------------------------------------------------------
__global__ __launch_bounds__(256) void reduce_kernel(
    const float* __restrict__ part, float* __restrict__ y,
    float* __restrict__ norm, int nslots)
{
    const int tid = threadIdx.x;
    const int b  = blockIdx.x & 7;
    const int d0 = (((blockIdx.x >> 3) * 256) + tid) * 4;  // float4 slice
    float4 s = make_float4(0.f, 0.f, 0.f, 0.f);
#pragma unroll 4
    for (int p = 0; p < nslots; ++p) {
        float4 v = *(const float4*)&part[((size_t)p * BATCH + b) * DDIM + d0];
        s.x += v.x; s.y += v.y; s.z += v.z; s.w += v.w;
    }
    *(float4*)&y[(size_t)b * DDIM + d0] = s;
    float ab = fabsf(s.x) + fabsf(s.y) + fabsf(s.z) + fabsf(s.w);
    __shared__ float red[256];
    red[tid] = ab;
    __syncthreads();
    for (int st = 128; st > 0; st >>= 1) {
        if (tid < st) red[tid] += red[tid + st];
        __syncthreads();
    }
    if (tid == 0) FATOMIC(&norm[b], red[0]);   // sum|y| == sum feat_unnorm^2
}

// ---------------------------------------------------------------------------
// Kernel 4: fused signed-sqrt + L2-normalize + classifier GEMV.
// grid 64: block j owns d in [128j, 128j+128) for all batches.
// ---------------------------------------------------------------------------
__global__ __launch_bounds__(256) void logit_kernel(
    const float* __restrict__ y, const float* __restrict__ norm,
    const float* __restrict__ W, float* __restrict__ out)
{
    const int j = blockIdx.x;
    const int tid = threadIdx.x;
    __shared__ float fs[BATCH][128];                   // 4 KB
    for (int i = tid; i < BATCH * 128; i += 256) {
        int bb = i >> 7, dd = i & 127;
        float v = y[(size_t)bb * DDIM + j * 128 + dd];
        float inv = 1.0f / fmaxf(sqrtf(norm[bb]), 1e-12f);
        float f = copysignf(sqrtf(fabsf(v)), v) * inv;
        fs[bb][dd] = f;
        out[BATCH * NCLS + (size_t)bb * DDIM + j * 128 + dd] = f;
    }
    __syncthreads();
    if (tid < NCLS) {
        float a[BATCH];
#pragma unroll
        for (int bb = 0; bb < BATCH; ++bb) a[bb] = 0.0f;
        for (int dd = 0; dd < 128; ++dd) {
            float w = W[(size_t)(j * 128 + dd) * NCLS + tid];
#pragma unroll
            for (int bb = 0; bb < BATCH; ++bb) a[bb] += fs[bb][dd] * w;
        }
#pragma unroll
        for (int bb = 0; bb < BATCH; ++bb)
            FATOMIC(&out[bb * NCLS + tid], a[bb]);
    }
}

// ---------------------------------------------------------------------------
extern "C" void kernel_launch(void* const* d_in, const int* in_sizes, int n_in,
                              void* d_out, int out_size, void* d_ws, size_t ws_size,
                              hipStream_t stream)
{
    const float* x  = (const float*)d_in[0];
    const float* s1 = (const float*)d_in[1];
    const float* s2 = (const float*)d_in[2];
    const float* W  = (const float*)d_in[3];
    const float* bc = (const float*)d_in[4];
    const int*   h1 = (const int*)d_in[5];
    const int*   h2 = (const int*)d_in[6];
    float* out = (float*)d_out;

    const size_t ybytes  = (size_t)BATCH * DDIM * sizeof(float);
    const size_t xhbytes = (size_t)BATCH * CH * KPAD * sizeof(_Float16);

    // Prefer exclusive mode: part = 136 slots (34 MB), plain-store flush.
    // Fallback (ws too small): 68 shared slots + atomic flush (R4 scheme).
    size_t partbytes = (size_t)NPAIR * BATCH * DDIM * sizeof(float);
    int exclusive = (ws_size >= partbytes + ybytes + 128 + xhbytes);
    if (!exclusive)
        partbytes = (size_t)NSLOT * BATCH * DDIM * sizeof(float);
    const int nslots = exclusive ? NPAIR : NSLOT;

    // ws layout: part | y (first 32KB doubles as metaG until reduce) | norm | xh
    char* ws = (char*)d_ws;
    float* part = (float*)ws;
    float* y    = (float*)(ws + partbytes);
    float4* metaG = (float4*)(ws + partbytes);         // overlay on y region
    float* norm = (float*)(ws + partbytes + ybytes);
    _Float16* xh = (_Float16*)(ws + partbytes + ybytes + 128);

    split_kernel<<<(BATCH * CH * KPAD / 4 + 255) / 256, 256, 0, stream>>>(
        x, xh, part, norm, s1, h1, s2, h2, metaG, bc, out, exclusive);

    gram_scatter_kernel<<<NPAIR * BATCH, 256, 0, stream>>>(
        xh, metaG, part, exclusive);

    reduce_kernel<<<64, 256, 0, stream>>>(part, y, norm, nslots);

    logit_kernel<<<64, 256, 0, stream>>>(y, norm, W, out);
}

// Round 6
// 180.769 us; speedup vs baseline: 2.2367x; 1.2258x over previous
//
#include <hip/hip_runtime.h>
#include <hip/hip_bf16.h>

// Problem constants (ResNet-50 CBP head)
#define BATCH 8
#define CH    2048
#define LSP   784          // H*W = 28*28
#define KPAD  832          // pad K to 13*64: full-128B-line k-stages
#define KSTAGE 13          // k-stages of BK=64 (2 MFMA k-substeps each)
#define DDIM  8192         // count-sketch dim (power of 2)
#define NCLS  200
#define NTILE 16           // 2048/128 tiles per dim
#define NPAIR 136          // NTILE*(NTILE+1)/2 symmetric tile pairs
#define NSLOT 68           // fallback: part slots per batch (2 blocks/slot)
#define FXSCALE 8192.0f    // fixed-point scale 2^13 (split as 64*128 into meta)
#define FXINV   (1.0f/8192.0f)

typedef _Float16 f16x8 __attribute__((ext_vector_type(8)));
typedef _Float16 f16x4 __attribute__((ext_vector_type(4)));
typedef float    f32x4 __attribute__((ext_vector_type(4)));

#define FATOMIC(p, v) unsafeAtomicAdd((p), (v))

// ---------------------------------------------------------------------------
// Kernel 1: convert x (fp32 [B,C,784]) to fp16 [B,C,KPAD] (zero-pad K).
// Also: zero norm, bias-seed logits, build the packed scatter-meta table
// metaG[c] = (s1[c]*64, h1[c], s2[c]*128, h2[c]) (2^13 fixed-point scale
// rides the s1*s2 product), and -- ONLY in atomic-fallback mode -- zero part.
// ---------------------------------------------------------------------------
__global__ __launch_bounds__(256) void split_kernel(
    const float* __restrict__ x,
    _Float16* __restrict__ xh,
    float* __restrict__ part, float* __restrict__ norm,
    const float* __restrict__ s1, const int* __restrict__ h1,
    const float* __restrict__ s2, const int* __restrict__ h2,
    float4* __restrict__ metaG,
    const float* __restrict__ bc, float* __restrict__ out,
    int exclusive)
{
    int idx = blockIdx.x * 256 + threadIdx.x;          // vec4 index
    if (!exclusive && idx < NSLOT * BATCH * DDIM / 4)  // zero part (fallback)
        *(float4*)&part[idx * 4] = make_float4(0.f, 0.f, 0.f, 0.f);
    if (idx < CH)
        metaG[idx] = make_float4(s1[idx] * 64.0f, __int_as_float(h1[idx]),
                                 s2[idx] * 128.0f, __int_as_float(h2[idx]));
    if (idx < BATCH) norm[idx] = 0.0f;
    if (idx < BATCH * NCLS) out[idx] = bc[idx % NCLS]; // bias-seed logits
    if (idx >= BATCH * CH * KPAD / 4) return;
    int v  = idx * 4;
    int bc_ = v / KPAD;
    int l  = v - bc_ * KPAD;                           // multiple of 4
    float4 xv = make_float4(0.f, 0.f, 0.f, 0.f);
    if (l < LSP)                                       // LSP%4==0: uniform per vec
        xv = *(const float4*)&x[(size_t)bc_ * LSP + l];
    f16x4 hv;
    hv[0] = (_Float16)xv.x; hv[1] = (_Float16)xv.y;
    hv[2] = (_Float16)xv.z; hv[3] = (_Float16)xv.w;
    *(f16x4*)&xh[v] = hv;
}

// ---------------------------------------------------------------------------
// Kernel 2: symmetric Gram tile + count-sketch scatter (int32 LDS histogram).
// R6 theory: R5's remaining 100us is k-loop L2 LINE traffic -- direct-load
// fragments touch 16 strided lines per instr at 50% line use, and each tile
// is read twice (2 waves share each half) => ~0.9-1.8 GB of line traffic.
// Fix: stage tiles in LDS ONCE per block with full-line (128B/row) chunks:
// KPAD=832 = 13 stages of BK=64; global_load_lds 16B/lane, 8 lanes/row.
// LDS reads XOR-swizzled (chunk ^= row&7; pre-swizzled global source +
// swizzled ds_read, linear LDS dest -- guide rule 21) to kill the
// stride-128B bank conflict. k order unchanged -> numerics identical.
// Scatter: banked ds_add_u32 (R4). Flush: exclusive slot plain stores (R5).
// LDS 64 KB (smA 16 + smB 16 + bins 32) -> 2 blocks/CU.
// grid = 1088: batch = id&7 (one batch per XCD), pair = id>>3.
// ---------------------------------------------------------------------------
__device__ __forceinline__ void stage64(
    const _Float16* __restrict__ src,   // xh + (b*CH + tile*128)*KPAD
    unsigned short* lds,                // 128x64-half tile, linear
    int wv, int lane, int s)
{
    const int rowi = lane >> 3;             // 0..7: row within instruction
    const int gc   = (lane & 7) ^ rowi;     // pre-swizzled global 8-half chunk
    const _Float16* g0 = src + (size_t)rowi * KPAD + s * 64 + gc * 8;
#pragma unroll
    for (int q = 0; q < 4; ++q) {
        const int r0 = wv * 32 + q * 8;     // 8 rows per instruction
        __builtin_amdgcn_global_load_lds(
            (__attribute__((address_space(1))) void*)(g0 + (size_t)r0 * KPAD),
            (__attribute__((address_space(3))) void*)(lds + r0 * 64),
            16, 0, 0);
    }
}

__global__ __launch_bounds__(256, 2) void gram_scatter_kernel(
    const _Float16* __restrict__ xh,
    const float4* __restrict__ metaG,
    float* __restrict__ part,
    int exclusive)
{
    __shared__ __align__(16) unsigned short smA[128 * 64];   // 16 KB
    __shared__ __align__(16) unsigned short smB[128 * 64];   // 16 KB
    __shared__ __align__(16) int bins[DDIM];                 // 32 KB

    const int tid  = threadIdx.x;
    const int lane = tid & 63;
    const int wv   = tid >> 6;
    const int b    = blockIdx.x & 7;       // batch in low bits -> one batch/XCD
    const int pidx = blockIdx.x >> 3;      // triangular pair index

    for (int i = tid; i < DDIM; i += 256) bins[i] = 0;

    // Triangular decode: pidx in [0,136) -> (tM, tN), tM <= tN, row-major
    int tM = 0, tN = 0;
    {
        int i = pidx;
#pragma unroll 1
        for (int t = 0; t < NTILE; ++t) {
            int cnt = NTILE - t;
            if (i < cnt) { tM = t; tN = t + i; break; }
            i -= cnt;
        }
    }
    const bool diag = (tM == tN);

    const int wrow = (wv >> 1) * 64;    // wave's 64x64 subtile origin
    const int wcol = (wv & 1) * 64;
    const int rsel = lane & 15;
    const int khi  = lane >> 4;         // k 8-half group within a k-substep

    const _Float16* srcA = xh + ((size_t)b * CH + (size_t)tM * 128) * KPAD;
    const _Float16* srcB = xh + ((size_t)b * CH + (size_t)tN * 128) * KPAD;
    const unsigned short* fragB = diag ? smA : smB;

    f32x4 acc[4][4];
    const f32x4 zv = {0.0f, 0.0f, 0.0f, 0.0f};
#pragma unroll
    for (int mi = 0; mi < 4; ++mi)
#pragma unroll
        for (int ni = 0; ni < 4; ++ni) acc[mi][ni] = zv;

    // Staged k-loop: 13 stages x {stage 16(32)KB, barrier, 2x(8 ds_read_b128
    // + 16 MFMA), barrier}. First barrier also orders bins zero-init.
#pragma unroll 1
    for (int s = 0; s < KSTAGE; ++s) {
        stage64(srcA, smA, wv, lane, s);
        if (!diag) stage64(srcB, smB, wv, lane, s);
        __syncthreads();                 // (vmcnt(0) drain: loads landed)
#pragma unroll
        for (int t = 0; t < 2; ++t) {
            // swizzled chunk: global chunk (t*4+khi) lives at LDS chunk
            // (t*4+khi)^(row&7); row&7 == rsel&7 for all fragments here.
            const int co = ((((t << 2) + khi) ^ (rsel & 7)) << 3);
            f16x8 ah[4], bh[4];
#pragma unroll
            for (int i = 0; i < 4; ++i) {
                ah[i] = *(const f16x8*)&smA[(wrow + i * 16 + rsel) * 64 + co];
                bh[i] = *(const f16x8*)&fragB[(wcol + i * 16 + rsel) * 64 + co];
            }
#pragma unroll
            for (int mi = 0; mi < 4; ++mi)
#pragma unroll
                for (int ni = 0; ni < 4; ++ni)
                    acc[mi][ni] = __builtin_amdgcn_mfma_f32_16x16x32_f16(
                        ah[mi], bh[ni], acc[mi][ni], 0, 0, 0);
        }
        __syncthreads();                 // all reads done before next stage
    }

    // Column meta: one packed float4 per c2 (VMEM, L2-hot). s-values carry
    // the fixed-point scale (s1*64, s2*128).
    const int c2b = tN * 128 + wcol + rsel;
    int   h1c[4], h2c[4]; float s1c[4], s2c[4];
#pragma unroll
    for (int ni = 0; ni < 4; ++ni) {
        float4 cm = metaG[c2b + ni * 16];
        s1c[ni] = cm.x; h1c[ni] = __float_as_int(cm.y);
        s2c[ni] = cm.z; h2c[ni] = __float_as_int(cm.w);
    }

    // Scatter the 128x128 Gram tile into the LDS int histogram.
    // C/D layout (m89-verified): col = lane&15, row = (lane>>4)*4 + reg
    // Row meta also via VMEM -> zero lgkmcnt-ordered ops between ds_adds.
    const int rowbase = tM * 128 + wrow + (khi << 2);
#pragma unroll
    for (int mi = 0; mi < 4; ++mi) {
        float4 rm[4];
#pragma unroll
        for (int r = 0; r < 4; ++r) rm[r] = metaG[rowbase + mi * 16 + r];
#pragma unroll
        for (int r = 0; r < 4; ++r) {
            const float s1r = rm[r].x, s2r = rm[r].z;
            const int h1r = __float_as_int(rm[r].y);
            const int h2r = __float_as_int(rm[r].w);
#pragma unroll
            for (int ni = 0; ni < 4; ++ni) {
                float g = acc[mi][ni][r];
                atomicAdd(&bins[(h1r + h2c[ni]) & (DDIM - 1)],
                          (int)(s1r * s2c[ni] * g));
                if (!diag)
                    atomicAdd(&bins[(h1c[ni] + h2r) & (DDIM - 1)],
                              (int)(s1c[ni] * s2r * g));
            }
        }
    }

    __syncthreads();   // all scatters into bins complete

    if (exclusive) {
        // Exclusive slot: plain coalesced float4 stores through L2.
        float* pbase = part + ((size_t)(pidx * BATCH + b) * DDIM);
#pragma unroll 4
        for (int i = tid; i < DDIM / 4; i += 256) {
            int4 v = *(const int4*)&bins[i * 4];
            float4 f = make_float4((float)v.x * FXINV, (float)v.y * FXINV,
                                   (float)v.z * FXINV, (float)v.w * FXINV);
            *(float4*)&pbase[i * 4] = f;
        }
    } else {
        // Fallback: 68 shared slots, fp32 global atomics, rotated start.
        float* pbase = part + ((size_t)((pidx % NSLOT) * BATCH + b) * DDIM);
        const int rot = (blockIdx.x & 31) << 8;
        for (int i = tid; i < DDIM; i += 256) {
            int j = (i + rot) & (DDIM - 1);
            int v = bins[j];
            if (v != 0) FATOMIC(&pbase[j], (float)v * FXINV);
        }
    }
}

// ---------------------------------------------------------------------------
// Kernel 3: y[b,d] = sum over nslots part slots; norm[b] += sum|y|.
// grid 64 x 256: one float4 of d per thread. batch = blockIdx&7 keeps each
// batch's reads on the XCD whose L2 holds that batch's freshly-written part.
// NOTE: overwrites y, whose first 32 KB doubled as metaG for the (already
// finished) gram kernel -- intentional workspace reuse.
// ---------------------------------------------------------------------------
__global__ __launch_bounds__(256) void reduce_kernel(
    const float* __restrict__ part, float* __restrict__ y,
    float* __restrict__ norm, int nslots)
{
    const int tid = threadIdx.x;
    const int b  = blockIdx.x & 7;
    const int d0 = (((blockIdx.x >> 3) * 256) + tid) * 4;  // float4 slice
    float4 s = make_float4(0.f, 0.f, 0.f, 0.f);
#pragma unroll 4
    for (int p = 0; p < nslots; ++p) {
        float4 v = *(const float4*)&part[((size_t)p * BATCH + b) * DDIM + d0];
        s.x += v.x; s.y += v.y; s.z += v.z; s.w += v.w;
    }
    *(float4*)&y[(size_t)b * DDIM + d0] = s;
    float ab = fabsf(s.x) + fabsf(s.y) + fabsf(s.z) + fabsf(s.w);
    __shared__ float red[256];
    red[tid] = ab;
    __syncthreads();
    for (int st = 128; st > 0; st >>= 1) {
        if (tid < st) red[tid] += red[tid + st];
        __syncthreads();
    }
    if (tid == 0) FATOMIC(&norm[b], red[0]);   // sum|y| == sum feat_unnorm^2
}

// ---------------------------------------------------------------------------
// Kernel 4: fused signed-sqrt + L2-normalize + classifier GEMV.
// grid 64: block j owns d in [128j, 128j+128) for all batches.
// ---------------------------------------------------------------------------
__global__ __launch_bounds__(256) void logit_kernel(
    const float* __restrict__ y, const float* __restrict__ norm,
    const float* __restrict__ W, float* __restrict__ out)
{
    const int j = blockIdx.x;
    const int tid = threadIdx.x;
    __shared__ float fs[BATCH][128];                   // 4 KB
    for (int i = tid; i < BATCH * 128; i += 256) {
        int bb = i >> 7, dd = i & 127;
        float v = y[(size_t)bb * DDIM + j * 128 + dd];
        float inv = 1.0f / fmaxf(sqrtf(norm[bb]), 1e-12f);
        float f = copysignf(sqrtf(fabsf(v)), v) * inv;
        fs[bb][dd] = f;
        out[BATCH * NCLS + (size_t)bb * DDIM + j * 128 + dd] = f;
    }
    __syncthreads();
    if (tid < NCLS) {
        float a[BATCH];
#pragma unroll
        for (int bb = 0; bb < BATCH; ++bb) a[bb] = 0.0f;
        for (int dd = 0; dd < 128; ++dd) {
            float w = W[(size_t)(j * 128 + dd) * NCLS + tid];
#pragma unroll
            for (int bb = 0; bb < BATCH; ++bb) a[bb] += fs[bb][dd] * w;
        }
#pragma unroll
        for (int bb = 0; bb < BATCH; ++bb)
            FATOMIC(&out[bb * NCLS + tid], a[bb]);
    }
}

// ---------------------------------------------------------------------------
extern "C" void kernel_launch(void* const* d_in, const int* in_sizes, int n_in,
                              void* d_out, int out_size, void* d_ws, size_t ws_size,
                              hipStream_t stream)
{
    const float* x  = (const float*)d_in[0];
    const float* s1 = (const float*)d_in[1];
    const float* s2 = (const float*)d_in[2];
    const float* W  = (const float*)d_in[3];
    const float* bc = (const float*)d_in[4];
    const int*   h1 = (const int*)d_in[5];
    const int*   h2 = (const int*)d_in[6];
    float* out = (float*)d_out;

    const size_t ybytes  = (size_t)BATCH * DDIM * sizeof(float);
    const size_t xhbytes = (size_t)BATCH * CH * KPAD * sizeof(_Float16);

    // Prefer exclusive mode: part = 136 slots (34 MB), plain-store flush.
    // Fallback (ws too small): 68 shared slots + atomic flush (R4 scheme).
    size_t partbytes = (size_t)NPAIR * BATCH * DDIM * sizeof(float);
    int exclusive = (ws_size >= partbytes + ybytes + 128 + xhbytes);
    if (!exclusive)
        partbytes = (size_t)NSLOT * BATCH * DDIM * sizeof(float);
    const int nslots = exclusive ? NPAIR : NSLOT;

    // ws layout: part | y (first 32KB doubles as metaG until reduce) | norm | xh
    char* ws = (char*)d_ws;
    float* part = (float*)ws;
    float* y    = (float*)(ws + partbytes);
    float4* metaG = (float4*)(ws + partbytes);         // overlay on y region
    float* norm = (float*)(ws + partbytes + ybytes);
    _Float16* xh = (_Float16*)(ws + partbytes + ybytes + 128);

    split_kernel<<<(BATCH * CH * KPAD / 4 + 255) / 256, 256, 0, stream>>>(
        x, xh, part, norm, s1, h1, s2, h2, metaG, bc, out, exclusive);

    gram_scatter_kernel<<<NPAIR * BATCH, 256, 0, stream>>>(
        xh, metaG, part, exclusive);

    reduce_kernel<<<64, 256, 0, stream>>>(part, y, norm, nslots);

    logit_kernel<<<64, 256, 0, stream>>>(y, norm, W, out);
}